// Round 1
// baseline (1692.691 us; speedup 1.0000x reference)
//
#include <hip/hip_runtime.h>
#include <math.h>

#define T_STEPS 50
#define D_IN    620
#define N1      200
#define N2      100
#define N3      11
#define BATCH   4096

// Synaptic kernel K (k=0..9), t = k-5: t<0 -> -0.5*exp(t), t>=0 -> exp(-t/2)
__device__ __constant__ float KV[10] = {
    -0.0033689735f, -0.0091578194f, -0.0248935342f, -0.0676676416f, -0.1839397206f,
     1.0f,           0.6065306597f,  0.3678794412f,  0.2231301601f,  0.1353352832f };
// KS[k+1] = exp(-(k+1)/2), k=0..8
__device__ __constant__ float KS_TAIL[9] = {
    0.6065306597f, 0.3678794412f, 0.2231301601f, 0.1353352832f, 0.0820849986f,
    0.0497870684f, 0.0301973834f, 0.0183156389f, 0.0111089965f };

__device__ __forceinline__ float sigm10(float x) { return 1.0f / (1.0f + __expf(-10.0f * x)); }
__device__ __forceinline__ float swishf(float v) { return v / (1.0f + __expf(-10.0f * v)); }

// ---------------------------------------------------------------------------
// Kernel 0: transpose W2 [100][200] -> W2T [200][100]
// ---------------------------------------------------------------------------
__global__ void transpose_w2(const float* __restrict__ W2, float* __restrict__ W2T) {
    int i = blockIdx.x * 256 + threadIdx.x;
    if (i < N2 * N1) {
        int k = i / N2, m = i % N2;
        W2T[i] = W2[m * N1 + k];
    }
}

// ---------------------------------------------------------------------------
// Kernel 1: per batch element b: h1[50][200] = swish(x[b] @ W1^T), then causal
// 10-tap conv over t -> syn2[b][50][200].  fp32 tiled GEMM, h1 stays in LDS.
// ---------------------------------------------------------------------------
__global__ __launch_bounds__(256) void gemm1_conv(const float* __restrict__ x,
                                                  const float* __restrict__ W1,
                                                  float* __restrict__ syn2) {
    __shared__ float smem[10000];            // 40 KB, reused: [As|Bs] then h1s
    float* As  = smem;                        // [50][21]
    float* Bs  = smem + 1056;                 // [20][204]
    float* h1s = smem;                        // [50][200] after GEMM

    const int b   = blockIdx.x;
    const int tid = threadIdx.x;
    const int mg  = tid / 25;                 // 0..10 (active < 10) -> rows 5*mg..5*mg+4
    const int ng  = tid % 25;                 // col groups: {4ng..4ng+3, 100+4ng..100+4ng+3}
    const bool act = (mg < 10);
    const int n0a = 4 * ng;
    const int n0b = 100 + 4 * ng;

    float acc[5][8];
#pragma unroll
    for (int i = 0; i < 5; ++i)
#pragma unroll
        for (int j = 0; j < 8; ++j) acc[i][j] = 0.0f;

    const float* xb = x + (size_t)b * (T_STEPS * D_IN);

    for (int k0 = 0; k0 < D_IN; k0 += 20) {
        for (int idx = tid; idx < 1000; idx += 256) {
            int m = idx / 20, kk = idx % 20;
            As[m * 21 + kk] = xb[m * D_IN + k0 + kk];
        }
        for (int idx = tid; idx < 4000; idx += 256) {
            int n = idx / 20, kk = idx % 20;
            Bs[kk * 204 + n] = W1[n * D_IN + k0 + kk];
        }
        __syncthreads();
        if (act) {
#pragma unroll
            for (int kk = 0; kk < 20; ++kk) {
                float a[5];
#pragma unroll
                for (int i = 0; i < 5; ++i) a[i] = As[(5 * mg + i) * 21 + kk];
                const float4 b0 = *(const float4*)&Bs[kk * 204 + n0a];
                const float4 b1 = *(const float4*)&Bs[kk * 204 + n0b];
                float bb[8] = { b0.x, b0.y, b0.z, b0.w, b1.x, b1.y, b1.z, b1.w };
#pragma unroll
                for (int i = 0; i < 5; ++i)
#pragma unroll
                    for (int j = 0; j < 8; ++j)
                        acc[i][j] = fmaf(a[i], bb[j], acc[i][j]);
            }
        }
        __syncthreads();
    }

    // swish epilogue -> h1s (overlaps As/Bs; safe after barrier above)
    if (act) {
#pragma unroll
        for (int i = 0; i < 5; ++i) {
            const int row = (5 * mg + i) * 200;
            float4 v0, v1;
            v0.x = swishf(acc[i][0]); v0.y = swishf(acc[i][1]);
            v0.z = swishf(acc[i][2]); v0.w = swishf(acc[i][3]);
            v1.x = swishf(acc[i][4]); v1.y = swishf(acc[i][5]);
            v1.z = swishf(acc[i][6]); v1.w = swishf(acc[i][7]);
            *(float4*)&h1s[row + n0a] = v0;
            *(float4*)&h1s[row + n0b] = v1;
        }
    }
    __syncthreads();

    // causal conv over t with KV, write syn2
    float* syn2b = syn2 + (size_t)b * (T_STEPS * N1);
    for (int idx = tid; idx < T_STEPS * N1; idx += 256) {
        int t = idx / N1, n = idx % N1;
        float s = 0.0f;
#pragma unroll
        for (int k = 0; k < 10; ++k) {
            if (k <= t) s = fmaf(KV[k], h1s[(t - k) * N1 + n], s);
        }
        syn2b[idx] = s;
    }
}

// ---------------------------------------------------------------------------
// Kernel 2: recurrent scan, 8 batch elems per 256-thread block.
// Histories live in registers (static indexing); s2/h2/s3/h3 via LDS.
// ---------------------------------------------------------------------------
__global__ __launch_bounds__(256) void snn_scan(const float* __restrict__ syn2,
                                                const float* __restrict__ W2T,  // [200][100]
                                                const float* __restrict__ W3,   // [11][100]
                                                float* __restrict__ out) {
    __shared__ float s2buf[8][200];
    __shared__ float h2buf[8][100];
    __shared__ float s3buf[8][100];
    __shared__ float h3buf[8][16];
    __shared__ float W3s[N3 * N2];        // 1100
    __shared__ float W2s[100 * 100];      // W2T rows k=0..99 staged (40 KB)

    const int tid = threadIdx.x;
    const int g   = tid >> 5;             // 0..7 elem in block
    const int c   = tid & 31;             // lane within elem group
    const long b  = (long)blockIdx.x * 8 + g;

    const int NL2 = (c < 8) ? 7 : 6;      // layer-2 channels n = c + 32j
    const int NL3 = (c < 4) ? 4 : 3;      // layer-3 channels m = c + 32j

    float sl2h[9][7] = {};
    float h2h[9][4]  = {};
    float sl3h[9][4] = {};
    float h3h[9]     = {};
    float sl4h[9]    = {};
    float acc        = 0.0f;

    for (int i = tid; i < N3 * N2; i += 256) W3s[i] = W3[i];
    for (int i = tid; i < 100 * 100; i += 256) W2s[i] = W2T[i];
    __syncthreads();

    const float* syn2b = syn2 + b * (T_STEPS * N1);

    for (int t = 0; t < T_STEPS; ++t) {
        // ---- P1: layer 2 (owners) ----
#pragma unroll
        for (int j = 0; j < 7; ++j) {
            if (j < NL2) {
                const int n = c + 32 * j;
                float mem2 = syn2b[t * N1 + n];
#pragma unroll
                for (int k = 0; k < 9; ++k) mem2 = fmaf(-KS_TAIL[k], sl2h[k][j], mem2);
                const float s2  = sigm10(mem2 - 0.5f);
                const float sl2 = s2 * mem2;
#pragma unroll
                for (int k = 8; k > 0; --k) sl2h[k][j] = sl2h[k - 1][j];
                sl2h[0][j] = sl2;
                s2buf[g][n] = s2;
            }
        }
        __syncthreads();

        // ---- P2: GEMM2  h2 = swish(s2 @ W2^T)  (200 active threads) ----
        if (tid < 200) {
            const int q  = tid / 100;         // g-group 0/1 (elems 4q..4q+3)
            const int m2 = tid - q * 100;     // output channel 0..99
            const int gb = q * 4;
            float a[4] = { 0, 0, 0, 0 };
#pragma unroll 2
            for (int k0 = 0; k0 < 100; k0 += 4) {
                float w[4];
#pragma unroll
                for (int kk = 0; kk < 4; ++kk) w[kk] = W2s[(k0 + kk) * 100 + m2];
#pragma unroll
                for (int i = 0; i < 4; ++i) {
                    const float4 sv = *(const float4*)&s2buf[gb + i][k0];
                    a[i] = fmaf(sv.x, w[0], a[i]);
                    a[i] = fmaf(sv.y, w[1], a[i]);
                    a[i] = fmaf(sv.z, w[2], a[i]);
                    a[i] = fmaf(sv.w, w[3], a[i]);
                }
            }
#pragma unroll 2
            for (int k0 = 100; k0 < 200; k0 += 4) {
                float w[4];
#pragma unroll
                for (int kk = 0; kk < 4; ++kk) w[kk] = W2T[(k0 + kk) * 100 + m2];
#pragma unroll
                for (int i = 0; i < 4; ++i) {
                    const float4 sv = *(const float4*)&s2buf[gb + i][k0];
                    a[i] = fmaf(sv.x, w[0], a[i]);
                    a[i] = fmaf(sv.y, w[1], a[i]);
                    a[i] = fmaf(sv.z, w[2], a[i]);
                    a[i] = fmaf(sv.w, w[3], a[i]);
                }
            }
#pragma unroll
            for (int i = 0; i < 4; ++i) h2buf[gb + i][m2] = swishf(a[i]);
        }
        __syncthreads();

        // ---- P3: layer 3 (owners) ----
#pragma unroll
        for (int j = 0; j < 4; ++j) {
            if (j < NL3) {
                const int m = c + 32 * j;
                const float hm = h2buf[g][m];
                float mem3 = KV[0] * hm;
#pragma unroll
                for (int k = 0; k < 9; ++k) mem3 = fmaf(KV[k + 1], h2h[k][j], mem3);
#pragma unroll
                for (int k = 0; k < 9; ++k) mem3 = fmaf(-KS_TAIL[k], sl3h[k][j], mem3);
                const float s3  = sigm10(mem3 - 0.5f);
                const float sl3 = s3 * mem3;
#pragma unroll
                for (int k = 8; k > 0; --k) { h2h[k][j] = h2h[k - 1][j]; sl3h[k][j] = sl3h[k - 1][j]; }
                h2h[0][j]  = hm;
                sl3h[0][j] = sl3;
                s3buf[g][m] = s3;
            }
        }
        __syncthreads();

        // ---- P4: GEMM3  h3 = swish(s3 @ W3^T)  (88 active threads) ----
        if (tid < 88) {
            const int gg = tid / 11, o = tid % 11;
            float a = 0.0f;
#pragma unroll 5
            for (int m = 0; m < 100; m += 4) {
                const float4 sv = *(const float4*)&s3buf[gg][m];
                const float4 wv = *(const float4*)&W3s[o * 100 + m];
                a = fmaf(sv.x, wv.x, a);
                a = fmaf(sv.y, wv.y, a);
                a = fmaf(sv.z, wv.z, a);
                a = fmaf(sv.w, wv.w, a);
            }
            h3buf[gg][o] = swishf(a);
        }
        __syncthreads();

        // ---- P5: layer 4 (owners, c<11) ----
        if (c < N3) {
            const float h3 = h3buf[g][c];
            float mem4 = KV[0] * h3;
#pragma unroll
            for (int k = 0; k < 9; ++k) mem4 = fmaf(KV[k + 1], h3h[k], mem4);
#pragma unroll
            for (int k = 0; k < 9; ++k) mem4 = fmaf(-KS_TAIL[k], sl4h[k], mem4);
            const float s4  = sigm10(mem4 - 0.5f);
            const float sl4 = s4 * mem4;
#pragma unroll
            for (int k = 8; k > 0; --k) { h3h[k] = h3h[k - 1]; sl4h[k] = sl4h[k - 1]; }
            h3h[0]  = h3;
            sl4h[0] = sl4;
            acc += s4;
        }
        __syncthreads();   // protect LDS buffers for next step
    }

    if (c < N3) out[b * N3 + c] = acc * 0.02f;
}

// ---------------------------------------------------------------------------
extern "C" void kernel_launch(void* const* d_in, const int* in_sizes, int n_in,
                              void* d_out, int out_size, void* d_ws, size_t ws_size,
                              hipStream_t stream) {
    const float* x  = (const float*)d_in[0];
    const float* W1 = (const float*)d_in[1];
    const float* W2 = (const float*)d_in[2];
    const float* W3 = (const float*)d_in[3];
    float* out = (float*)d_out;

    float* syn2 = (float*)d_ws;                              // 4096*50*200 f32 = 163.84 MB
    float* W2T  = syn2 + (size_t)BATCH * T_STEPS * N1;       // 200*100 f32

    transpose_w2<<<(N1 * N2 + 255) / 256, 256, 0, stream>>>(W2, W2T);
    gemm1_conv<<<BATCH, 256, 0, stream>>>(x, W1, syn2);
    snn_scan<<<BATCH / 8, 256, 0, stream>>>(syn2, W2T, W3, out);
}

// Round 3
// 909.251 us; speedup vs baseline: 1.8616x; 1.8616x over previous
//
#include <hip/hip_runtime.h>
#include <math.h>

#define T_STEPS 50
#define D_IN    620
#define N1      200
#define N2      100
#define N3      11
#define BATCH   4096

typedef short bf16x8 __attribute__((ext_vector_type(8)));
typedef float f32x4  __attribute__((ext_vector_type(4)));

// Synaptic kernel K (k=0..9), t = k-5: t<0 -> -0.5*exp(t), t>=0 -> exp(-t/2)
__device__ __constant__ float KV[10] = {
    -0.0033689735f, -0.0091578194f, -0.0248935342f, -0.0676676416f, -0.1839397206f,
     1.0f,           0.6065306597f,  0.3678794412f,  0.2231301601f,  0.1353352832f };
__device__ __constant__ float KS_TAIL[9] = {
    0.6065306597f, 0.3678794412f, 0.2231301601f, 0.1353352832f, 0.0820849986f,
    0.0497870684f, 0.0301973834f, 0.0183156389f, 0.0111089965f };

__device__ __forceinline__ float sigm10(float x) { return 1.0f / (1.0f + __expf(-10.0f * x)); }
__device__ __forceinline__ float swishf(float v) { return v / (1.0f + __expf(-10.0f * v)); }

// split f32 into bf16 hi (truncated) + bf16 lo (truncated remainder)
__device__ __forceinline__ void split2(float x, unsigned short& hi, unsigned short& lo) {
    unsigned u = __float_as_uint(x);
    hi = (unsigned short)(u >> 16);
    float rem = x - __uint_as_float(u & 0xFFFF0000u);   // exact
    lo = (unsigned short)(__float_as_uint(rem) >> 16);
}

// ---------------------------------------------------------------------------
// W2 [100][200] -> W2T [200][100]
// ---------------------------------------------------------------------------
__global__ void transpose_w2(const float* __restrict__ W2, float* __restrict__ W2T) {
    int i = blockIdx.x * 256 + threadIdx.x;
    if (i < N2 * N1) {
        int k = i / N2, m = i % N2;
        W2T[i] = W2[m * N1 + k];
    }
}

// ---------------------------------------------------------------------------
// Prep W1 -> W1pre: per k-tile kt (20 tiles of K=32, zero-padded), parts hi/lo,
// rows n padded to 256, 32 bf16 per row stored with granule swizzle
// granule' = granule ^ ((n>>1)&3).  Tile = 32768 B, matches LDS image exactly.
// ---------------------------------------------------------------------------
__global__ void prep_w1(const float* __restrict__ W1, unsigned short* __restrict__ W1pre) {
    int i = blockIdx.x * 256 + threadIdx.x;           // 20*2*256*32 = 327680
    if (i >= 20 * 2 * 256 * 32) return;
    int kk = i & 31;
    int n  = (i >> 5) & 255;
    int p  = (i >> 13) & 1;
    int kt = i >> 14;
    int k  = kt * 32 + kk;
    float w = (n < N1 && k < D_IN) ? W1[n * D_IN + k] : 0.0f;
    unsigned short hi, lo; split2(w, hi, lo);
    int gsw = (kk >> 3) ^ ((n >> 1) & 3);
    int idx = kt * 16384 + p * 8192 + n * 32 + gsw * 8 + (kk & 7);
    W1pre[idx] = p ? lo : hi;
}

// ---------------------------------------------------------------------------
// MFMA GEMM1: h1[204800][200] = swish(x @ W1^T), 3-pass bf16 split precision.
// BM=256 (8 waves x 2 M-tiles), BN=208 (13 N-tiles), BK=32, double-buffered.
// LDS: A[2][256][32]f32 (granule^=(row&7)), B[2][2][256][32]bf16 (pre-swizzled).
// ---------------------------------------------------------------------------
__global__ __launch_bounds__(512) void gemm1_mfma(const float* __restrict__ x,
                                                  const unsigned short* __restrict__ W1pre,
                                                  float* __restrict__ h1) {
    extern __shared__ __align__(16) char smem[];

    const int tid = threadIdx.x;
    const int w   = tid >> 6;          // wave 0..7
    const int l   = tid & 63;
    const int j   = l >> 4;            // 0..3
    const int r16 = l & 15;
    const long row0 = (long)blockIdx.x * 256;
    const float* xblk = x + row0 * D_IN;

    f32x4 acc[2][13];
#pragma unroll
    for (int mt = 0; mt < 2; ++mt)
#pragma unroll
        for (int nt = 0; nt < 13; ++nt) acc[mt][nt] = (f32x4){0.f, 0.f, 0.f, 0.f};

    // async stage A tile kt (kt<=18): linear LDS dest, swizzled per-lane source
    auto stageA = [&](int kt, int bb) {
        float* Ab = (float*)(smem + bb * 32768);
#pragma unroll
        for (int it = 0; it < 4; ++it) {
            int s   = it * 8192 + w * 1024 + l * 16;              // LDS byte
            int row = s >> 7;
            int g   = ((s >> 4) & 7) ^ (row & 7);                 // source granule
            const float* src = xblk + row * D_IN + kt * 32 + g * 4;
            float* ldsb = Ab + (it * 2048 + w * 256);             // f32 units
            __builtin_amdgcn_global_load_lds(
                (const __attribute__((address_space(1))) unsigned int*)src,
                (__attribute__((address_space(3))) unsigned int*)ldsb, 16, 0, 0);
        }
    };
    // async stage B tile kt: pure linear copy (layout pre-swizzled in prep)
    auto stageB = [&](int kt, int bb) {
        unsigned short* Bb = (unsigned short*)(smem + 65536 + bb * 32768);
        const unsigned short* src = W1pre + kt * 16384;
#pragma unroll
        for (int it = 0; it < 4; ++it) {
            int offs = it * 4096 + w * 512 + l * 8;               // ushort units
            unsigned short* ldsb = Bb + (it * 4096 + w * 512);
            __builtin_amdgcn_global_load_lds(
                (const __attribute__((address_space(1))) unsigned int*)(src + offs),
                (__attribute__((address_space(3))) unsigned int*)ldsb, 16, 0, 0);
        }
    };
    // guarded tail stage for A (kt=19: cols 608..619 valid, rest zero)
    auto stageAtail = [&](int bb) {
        float* dst = (float*)(smem + bb * 32768);
        for (int idx = tid; idx < 8192; idx += 512) {
            int row = idx >> 5, c = idx & 31;
            float v = (c < 12) ? xblk[row * D_IN + 608 + c] : 0.0f;
            int g = (c >> 2) ^ (row & 7);
            dst[row * 32 + g * 4 + (c & 3)] = v;
        }
    };

    auto compute = [&](int bb) {
        const float* A = (const float*)(smem + bb * 32768);
        const unsigned short* B = (const unsigned short*)(smem + 65536 + bb * 32768);
        bf16x8 ah[2], al[2];
#pragma unroll
        for (int mt = 0; mt < 2; ++mt) {
            int r  = w * 32 + mt * 16 + r16;
            int g0 = (2 * j) ^ (r & 7), g1 = (2 * j + 1) ^ (r & 7);
            const float4 v0 = *(const float4*)(A + r * 32 + g0 * 4);
            const float4 v1 = *(const float4*)(A + r * 32 + g1 * 4);
            float vv[8] = { v0.x, v0.y, v0.z, v0.w, v1.x, v1.y, v1.z, v1.w };
#pragma unroll
            for (int e = 0; e < 8; ++e) {
                unsigned short hi, lo; split2(vv[e], hi, lo);
                ah[mt][e] = (short)hi; al[mt][e] = (short)lo;
            }
        }
#pragma unroll
        for (int nt = 0; nt < 13; ++nt) {
            int n  = nt * 16 + r16;
            int gs = j ^ ((n >> 1) & 3);
            const bf16x8 bh = *(const bf16x8*)(B + n * 32 + gs * 8);
            const bf16x8 bl = *(const bf16x8*)(B + 8192 + n * 32 + gs * 8);
#pragma unroll
            for (int mt = 0; mt < 2; ++mt) {
                acc[mt][nt] = __builtin_amdgcn_mfma_f32_16x16x32_bf16(ah[mt], bh, acc[mt][nt], 0, 0, 0);
                acc[mt][nt] = __builtin_amdgcn_mfma_f32_16x16x32_bf16(ah[mt], bl, acc[mt][nt], 0, 0, 0);
                acc[mt][nt] = __builtin_amdgcn_mfma_f32_16x16x32_bf16(al[mt], bh, acc[mt][nt], 0, 0, 0);
            }
        }
    };

    stageA(0, 0); stageB(0, 0);
    __syncthreads();                                   // drains vmcnt
    for (int kt = 0; kt < 20; ++kt) {
        const int cur = kt & 1, nxt = cur ^ 1;
        if (kt < 19) {
            if (kt + 1 == 19) stageAtail(nxt); else stageA(kt + 1, nxt);
            stageB(kt + 1, nxt);
        }
        compute(cur);
        __syncthreads();
    }

    // epilogue: D[(l>>4)*4+q][l&15] per 16x16 tile; apply swish, store f32
#pragma unroll
    for (int mt = 0; mt < 2; ++mt) {
        const long grow0 = row0 + w * 32 + mt * 16 + j * 4;
#pragma unroll
        for (int nt = 0; nt < 13; ++nt) {
            const int gcol = nt * 16 + r16;
            if (gcol < N1) {
#pragma unroll
                for (int q = 0; q < 4; ++q)
                    h1[(grow0 + q) * N1 + gcol] = swishf(acc[mt][nt][q]);
            }
        }
    }
}

// ---------------------------------------------------------------------------
// In-place causal conv: buf holds h1, overwritten with syn2 (per-b block)
// ---------------------------------------------------------------------------
__global__ __launch_bounds__(256) void conv_k(float* __restrict__ buf) {
    __shared__ float h1s[T_STEPS * N1];
    const int b = blockIdx.x, tid = threadIdx.x;
    float* p = buf + (size_t)b * (T_STEPS * N1);
    for (int i = tid; i < T_STEPS * N1 / 4; i += 256)
        ((float4*)h1s)[i] = ((const float4*)p)[i];
    __syncthreads();
    for (int i = tid; i < T_STEPS * N1; i += 256) {
        int t = i / N1, n = i - t * N1;
        float s = 0.0f;
#pragma unroll
        for (int k = 0; k < 10; ++k)
            if (k <= t) s = fmaf(KV[k], h1s[(t - k) * N1 + n], s);
        p[i] = s;
    }
}

// ---------------------------------------------------------------------------
// Recurrent scan (unchanged from passing round)
// ---------------------------------------------------------------------------
__global__ __launch_bounds__(256) void snn_scan(const float* __restrict__ syn2,
                                                const float* __restrict__ W2T,
                                                const float* __restrict__ W3,
                                                float* __restrict__ out) {
    __shared__ float s2buf[8][200];
    __shared__ float h2buf[8][100];
    __shared__ float s3buf[8][100];
    __shared__ float h3buf[8][16];
    __shared__ float W3s[N3 * N2];
    __shared__ float W2s[100 * 100];

    const int tid = threadIdx.x;
    const int g   = tid >> 5;
    const int c   = tid & 31;
    const long b  = (long)blockIdx.x * 8 + g;

    const int NL2 = (c < 8) ? 7 : 6;
    const int NL3 = (c < 4) ? 4 : 3;

    float sl2h[9][7] = {};
    float h2h[9][4]  = {};
    float sl3h[9][4] = {};
    float h3h[9]     = {};
    float sl4h[9]    = {};
    float acc        = 0.0f;

    for (int i = tid; i < N3 * N2; i += 256) W3s[i] = W3[i];
    for (int i = tid; i < 100 * 100; i += 256) W2s[i] = W2T[i];
    __syncthreads();

    const float* syn2b = syn2 + b * (T_STEPS * N1);

    for (int t = 0; t < T_STEPS; ++t) {
#pragma unroll
        for (int jj = 0; jj < 7; ++jj) {
            if (jj < NL2) {
                const int n = c + 32 * jj;
                float mem2 = syn2b[t * N1 + n];
#pragma unroll
                for (int k = 0; k < 9; ++k) mem2 = fmaf(-KS_TAIL[k], sl2h[k][jj], mem2);
                const float s2  = sigm10(mem2 - 0.5f);
                const float sl2 = s2 * mem2;
#pragma unroll
                for (int k = 8; k > 0; --k) sl2h[k][jj] = sl2h[k - 1][jj];
                sl2h[0][jj] = sl2;
                s2buf[g][n] = s2;
            }
        }
        __syncthreads();

        if (tid < 200) {
            const int q  = tid / 100;
            const int m2 = tid - q * 100;
            const int gb = q * 4;
            float a[4] = { 0, 0, 0, 0 };
#pragma unroll 2
            for (int k0 = 0; k0 < 100; k0 += 4) {
                float wv[4];
#pragma unroll
                for (int kk = 0; kk < 4; ++kk) wv[kk] = W2s[(k0 + kk) * 100 + m2];
#pragma unroll
                for (int i = 0; i < 4; ++i) {
                    const float4 sv = *(const float4*)&s2buf[gb + i][k0];
                    a[i] = fmaf(sv.x, wv[0], a[i]);
                    a[i] = fmaf(sv.y, wv[1], a[i]);
                    a[i] = fmaf(sv.z, wv[2], a[i]);
                    a[i] = fmaf(sv.w, wv[3], a[i]);
                }
            }
#pragma unroll 2
            for (int k0 = 100; k0 < 200; k0 += 4) {
                float wv[4];
#pragma unroll
                for (int kk = 0; kk < 4; ++kk) wv[kk] = W2T[(k0 + kk) * 100 + m2];
#pragma unroll
                for (int i = 0; i < 4; ++i) {
                    const float4 sv = *(const float4*)&s2buf[gb + i][k0];
                    a[i] = fmaf(sv.x, wv[0], a[i]);
                    a[i] = fmaf(sv.y, wv[1], a[i]);
                    a[i] = fmaf(sv.z, wv[2], a[i]);
                    a[i] = fmaf(sv.w, wv[3], a[i]);
                }
            }
#pragma unroll
            for (int i = 0; i < 4; ++i) h2buf[gb + i][m2] = swishf(a[i]);
        }
        __syncthreads();

#pragma unroll
        for (int jj = 0; jj < 4; ++jj) {
            if (jj < NL3) {
                const int m = c + 32 * jj;
                const float hm = h2buf[g][m];
                float mem3 = KV[0] * hm;
#pragma unroll
                for (int k = 0; k < 9; ++k) mem3 = fmaf(KV[k + 1], h2h[k][jj], mem3);
#pragma unroll
                for (int k = 0; k < 9; ++k) mem3 = fmaf(-KS_TAIL[k], sl3h[k][jj], mem3);
                const float s3  = sigm10(mem3 - 0.5f);
                const float sl3 = s3 * mem3;
#pragma unroll
                for (int k = 8; k > 0; --k) { h2h[k][jj] = h2h[k - 1][jj]; sl3h[k][jj] = sl3h[k - 1][jj]; }
                h2h[0][jj]  = hm;
                sl3h[0][jj] = sl3;
                s3buf[g][m] = s3;
            }
        }
        __syncthreads();

        if (tid < 88) {
            const int gg = tid / 11, o = tid % 11;
            float a = 0.0f;
#pragma unroll 5
            for (int m = 0; m < 100; m += 4) {
                const float4 sv = *(const float4*)&s3buf[gg][m];
                const float4 wv = *(const float4*)&W3s[o * 100 + m];
                a = fmaf(sv.x, wv.x, a);
                a = fmaf(sv.y, wv.y, a);
                a = fmaf(sv.z, wv.z, a);
                a = fmaf(sv.w, wv.w, a);
            }
            h3buf[gg][o] = swishf(a);
        }
        __syncthreads();

        if (c < N3) {
            const float h3 = h3buf[g][c];
            float mem4 = KV[0] * h3;
#pragma unroll
            for (int k = 0; k < 9; ++k) mem4 = fmaf(KV[k + 1], h3h[k], mem4);
#pragma unroll
            for (int k = 0; k < 9; ++k) mem4 = fmaf(-KS_TAIL[k], sl4h[k], mem4);
            const float s4  = sigm10(mem4 - 0.5f);
            const float sl4 = s4 * mem4;
#pragma unroll
            for (int k = 8; k > 0; --k) { h3h[k] = h3h[k - 1]; sl4h[k] = sl4h[k - 1]; }
            h3h[0]  = h3;
            sl4h[0] = sl4;
            acc += s4;
        }
        __syncthreads();
    }

    if (c < N3) out[b * N3 + c] = acc * 0.02f;
}

// ---------------------------------------------------------------------------
extern "C" void kernel_launch(void* const* d_in, const int* in_sizes, int n_in,
                              void* d_out, int out_size, void* d_ws, size_t ws_size,
                              hipStream_t stream) {
    const float* x  = (const float*)d_in[0];
    const float* W1 = (const float*)d_in[1];
    const float* W2 = (const float*)d_in[2];
    const float* W3 = (const float*)d_in[3];
    float* out = (float*)d_out;

    float* buf = (float*)d_ws;                          // h1 then syn2 in place: 163.84 MB
    float* W2T = buf + (size_t)BATCH * T_STEPS * N1;    // 20000 f32
    unsigned short* W1pre = (unsigned short*)(W2T + N1 * N2);  // 655360 B

    (void)hipFuncSetAttribute((const void*)gemm1_mfma,
                              hipFuncAttributeMaxDynamicSharedMemorySize, 131072);

    transpose_w2<<<(N1 * N2 + 255) / 256, 256, 0, stream>>>(W2, W2T);
    prep_w1<<<1280, 256, 0, stream>>>(W1, W1pre);
    gemm1_mfma<<<(BATCH * T_STEPS) / 256, 512, 131072, stream>>>(x, W1pre, buf);
    conv_k<<<BATCH, 256, 0, stream>>>(buf);
    snn_scan<<<BATCH / 8, 256, 0, stream>>>(buf, W2T, W3, out);
}

// Round 4
// 716.102 us; speedup vs baseline: 2.3638x; 1.2697x over previous
//
#include <hip/hip_runtime.h>
#include <math.h>

#define T_STEPS 50
#define D_IN    620
#define N1      200
#define N2      100
#define N3      11
#define BATCH   4096

typedef short bf16x8 __attribute__((ext_vector_type(8)));
typedef float f32x4  __attribute__((ext_vector_type(4)));

// Synaptic kernel K (k=0..9), t = k-5: t<0 -> -0.5*exp(t), t>=0 -> exp(-t/2)
__device__ __constant__ float KV[10] = {
    -0.0033689735f, -0.0091578194f, -0.0248935342f, -0.0676676416f, -0.1839397206f,
     1.0f,           0.6065306597f,  0.3678794412f,  0.2231301601f,  0.1353352832f };
__device__ __constant__ float KS_TAIL[9] = {
    0.6065306597f, 0.3678794412f, 0.2231301601f, 0.1353352832f, 0.0820849986f,
    0.0497870684f, 0.0301973834f, 0.0183156389f, 0.0111089965f };

__device__ __forceinline__ float sigm10(float x) { return 1.0f / (1.0f + __expf(-10.0f * x)); }
__device__ __forceinline__ float swishf(float v) { return v / (1.0f + __expf(-10.0f * v)); }

__device__ __forceinline__ void split2(float x, unsigned short& hi, unsigned short& lo) {
    unsigned u = __float_as_uint(x);
    hi = (unsigned short)(u >> 16);
    float rem = x - __uint_as_float(u & 0xFFFF0000u);   // exact
    lo = (unsigned short)(__float_as_uint(rem) >> 16);
}

// ---------------------------------------------------------------------------
// Prep W1 -> W1pre (unchanged; feeds gemm1_mfma LDS image)
// ---------------------------------------------------------------------------
__global__ void prep_w1(const float* __restrict__ W1, unsigned short* __restrict__ W1pre) {
    int i = blockIdx.x * 256 + threadIdx.x;           // 20*2*256*32 = 327680
    if (i >= 20 * 2 * 256 * 32) return;
    int kk = i & 31;
    int n  = (i >> 5) & 255;
    int p  = (i >> 13) & 1;
    int kt = i >> 14;
    int k  = kt * 32 + kk;
    float w = (n < N1 && k < D_IN) ? W1[n * D_IN + k] : 0.0f;
    unsigned short hi, lo; split2(w, hi, lo);
    int gsw = (kk >> 3) ^ ((n >> 1) & 3);
    int idx = kt * 16384 + p * 8192 + n * 32 + gsw * 8 + (kk & 7);
    W1pre[idx] = p ? lo : hi;
}

// ---------------------------------------------------------------------------
// Prep W2 -> per-wave MFMA B-fragments, hi/lo split, n padded to 128, k to 224.
// idx = ((wv*7+ks)*2+p)*512 + l*8 + e ; value = split(W2[n][k])[p],
// n = wv*16 + (l&15), k = ks*32 + (l>>4)*8 + e.  Total 57344 ushorts.
// ---------------------------------------------------------------------------
__global__ void prep_w2(const float* __restrict__ W2, unsigned short* __restrict__ W2pre2) {
    int i = blockIdx.x * 256 + threadIdx.x;
    if (i >= 57344) return;
    int e  = i & 7;
    int r  = i >> 3;
    int l  = r & 63;
    int r2 = r >> 6;
    int p  = r2 & 1;
    int r3 = r2 >> 1;           // wv*7 + ks
    int ks = r3 % 7;
    int wv = r3 / 7;
    int n  = wv * 16 + (l & 15);
    int k  = ks * 32 + (l >> 4) * 8 + e;
    float v = (n < N2 && k < N1) ? W2[n * N1 + k] : 0.0f;
    unsigned short hi, lo; split2(v, hi, lo);
    W2pre2[i] = p ? lo : hi;
}

// ---------------------------------------------------------------------------
// MFMA GEMM1 (unchanged, passing): h1 = swish(x @ W1^T)
// ---------------------------------------------------------------------------
__global__ __launch_bounds__(512) void gemm1_mfma(const float* __restrict__ x,
                                                  const unsigned short* __restrict__ W1pre,
                                                  float* __restrict__ h1) {
    extern __shared__ __align__(16) char smem[];

    const int tid = threadIdx.x;
    const int w   = tid >> 6;
    const int l   = tid & 63;
    const int j   = l >> 4;
    const int r16 = l & 15;
    const long row0 = (long)blockIdx.x * 256;
    const float* xblk = x + row0 * D_IN;

    f32x4 acc[2][13];
#pragma unroll
    for (int mt = 0; mt < 2; ++mt)
#pragma unroll
        for (int nt = 0; nt < 13; ++nt) acc[mt][nt] = (f32x4){0.f, 0.f, 0.f, 0.f};

    auto stageA = [&](int kt, int bb) {
        float* Ab = (float*)(smem + bb * 32768);
#pragma unroll
        for (int it = 0; it < 4; ++it) {
            int s   = it * 8192 + w * 1024 + l * 16;
            int row = s >> 7;
            int g   = ((s >> 4) & 7) ^ (row & 7);
            const float* src = xblk + row * D_IN + kt * 32 + g * 4;
            float* ldsb = Ab + (it * 2048 + w * 256);
            __builtin_amdgcn_global_load_lds(
                (const __attribute__((address_space(1))) unsigned int*)src,
                (__attribute__((address_space(3))) unsigned int*)ldsb, 16, 0, 0);
        }
    };
    auto stageB = [&](int kt, int bb) {
        unsigned short* Bb = (unsigned short*)(smem + 65536 + bb * 32768);
        const unsigned short* src = W1pre + kt * 16384;
#pragma unroll
        for (int it = 0; it < 4; ++it) {
            int offs = it * 4096 + w * 512 + l * 8;
            unsigned short* ldsb = Bb + (it * 4096 + w * 512);
            __builtin_amdgcn_global_load_lds(
                (const __attribute__((address_space(1))) unsigned int*)(src + offs),
                (__attribute__((address_space(3))) unsigned int*)ldsb, 16, 0, 0);
        }
    };
    auto stageAtail = [&](int bb) {
        float* dst = (float*)(smem + bb * 32768);
        for (int idx = tid; idx < 8192; idx += 512) {
            int row = idx >> 5, c = idx & 31;
            float v = (c < 12) ? xblk[row * D_IN + 608 + c] : 0.0f;
            int g = (c >> 2) ^ (row & 7);
            dst[row * 32 + g * 4 + (c & 3)] = v;
        }
    };

    auto compute = [&](int bb) {
        const float* A = (const float*)(smem + bb * 32768);
        const unsigned short* B = (const unsigned short*)(smem + 65536 + bb * 32768);
        bf16x8 ah[2], al[2];
#pragma unroll
        for (int mt = 0; mt < 2; ++mt) {
            int r  = w * 32 + mt * 16 + r16;
            int g0 = (2 * j) ^ (r & 7), g1 = (2 * j + 1) ^ (r & 7);
            const float4 v0 = *(const float4*)(A + r * 32 + g0 * 4);
            const float4 v1 = *(const float4*)(A + r * 32 + g1 * 4);
            float vv[8] = { v0.x, v0.y, v0.z, v0.w, v1.x, v1.y, v1.z, v1.w };
#pragma unroll
            for (int e = 0; e < 8; ++e) {
                unsigned short hi, lo; split2(vv[e], hi, lo);
                ah[mt][e] = (short)hi; al[mt][e] = (short)lo;
            }
        }
#pragma unroll
        for (int nt = 0; nt < 13; ++nt) {
            int n  = nt * 16 + r16;
            int gs = j ^ ((n >> 1) & 3);
            const bf16x8 bh = *(const bf16x8*)(B + n * 32 + gs * 8);
            const bf16x8 bl = *(const bf16x8*)(B + 8192 + n * 32 + gs * 8);
#pragma unroll
            for (int mt = 0; mt < 2; ++mt) {
                acc[mt][nt] = __builtin_amdgcn_mfma_f32_16x16x32_bf16(ah[mt], bh, acc[mt][nt], 0, 0, 0);
                acc[mt][nt] = __builtin_amdgcn_mfma_f32_16x16x32_bf16(ah[mt], bl, acc[mt][nt], 0, 0, 0);
                acc[mt][nt] = __builtin_amdgcn_mfma_f32_16x16x32_bf16(al[mt], bh, acc[mt][nt], 0, 0, 0);
            }
        }
    };

    stageA(0, 0); stageB(0, 0);
    __syncthreads();
    for (int kt = 0; kt < 20; ++kt) {
        const int cur = kt & 1, nxt = cur ^ 1;
        if (kt < 19) {
            if (kt + 1 == 19) stageAtail(nxt); else stageA(kt + 1, nxt);
            stageB(kt + 1, nxt);
        }
        compute(cur);
        __syncthreads();
    }

#pragma unroll
    for (int mt = 0; mt < 2; ++mt) {
        const long grow0 = row0 + w * 32 + mt * 16 + j * 4;
#pragma unroll
        for (int nt = 0; nt < 13; ++nt) {
            const int gcol = nt * 16 + r16;
            if (gcol < N1) {
#pragma unroll
                for (int q = 0; q < 4; ++q)
                    h1[(grow0 + q) * N1 + gcol] = swishf(acc[mt][nt][q]);
            }
        }
    }
}

// ---------------------------------------------------------------------------
// In-place causal conv (unchanged)
// ---------------------------------------------------------------------------
__global__ __launch_bounds__(256) void conv_k(float* __restrict__ buf) {
    __shared__ float h1s[T_STEPS * N1];
    const int b = blockIdx.x, tid = threadIdx.x;
    float* p = buf + (size_t)b * (T_STEPS * N1);
    for (int i = tid; i < T_STEPS * N1 / 4; i += 256)
        ((float4*)h1s)[i] = ((const float4*)p)[i];
    __syncthreads();
    for (int i = tid; i < T_STEPS * N1; i += 256) {
        int t = i / N1, n = i - t * N1;
        float s = 0.0f;
#pragma unroll
        for (int k = 0; k < 10; ++k)
            if (k <= t) s = fmaf(KV[k], h1s[(t - k) * N1 + n], s);
        p[i] = s;
    }
}

// ---------------------------------------------------------------------------
// Recurrent scan v2: 16 elems/block, 512 threads (8 waves), MFMA GEMM2.
//   A (s2) in LDS, hi/lo bf16, rows=elems stride 256 ushorts, granule^=(elem&7)
//   B (W2) per-wave fragments in REGISTERS (bh/bl[7]), loaded once.
//   D: h2[elem=(l>>4)*4+q][ch=wv*16+(l&15)]  (verified mapping from gemm1)
// ---------------------------------------------------------------------------
__global__ __launch_bounds__(512, 2) void snn_scan2(const float* __restrict__ syn2,
                                                    const unsigned short* __restrict__ W2pre2,
                                                    const float* __restrict__ W3,
                                                    float* __restrict__ out) {
    __shared__ __align__(16) unsigned short s2A[8192];  // [p][16][256] swizzled
    __shared__ __align__(16) float h2buf[16][132];
    __shared__ __align__(16) float s3buf[16][104];
    __shared__ __align__(16) float W3s[N3 * N2];        // 1100
    __shared__ __align__(16) float h3buf[192];          // [16][12]

    const int tid = threadIdx.x;
    const int g   = tid >> 5;          // elem group 0..15
    const int c   = tid & 31;
    const int wv  = tid >> 6;          // wave 0..7 = N-tile
    const int l   = tid & 63;
    const int m16 = l & 15;
    const int j2  = l >> 4;
    const long b  = (long)blockIdx.x * 16 + g;

    for (int i = tid; i < N3 * N2; i += 512) W3s[i] = W3[i];
    for (int i = tid; i < 8192; i += 512) s2A[i] = 0;   // zero k-pad once

    // B-fragments (registers, persistent): 14 x bf16x8 = 56 VGPR
    bf16x8 bh[7], bl[7];
    {
        const unsigned short* wp = W2pre2 + wv * 7168 + l * 8;
#pragma unroll
        for (int ks = 0; ks < 7; ++ks) {
            bh[ks] = *(const bf16x8*)(wp + ks * 1024);
            bl[ks] = *(const bf16x8*)(wp + ks * 1024 + 512);
        }
    }

    const int NL2 = (c < 8) ? 7 : 6;
    const int NL3 = (c < 4) ? 4 : 3;

    float sl2h[9][7] = {};
    float h2h[9][4]  = {};
    float sl3h[9][4] = {};
    float h3h[9]     = {};
    float sl4h[9]    = {};
    float accum      = 0.0f;

    const float* syn2b = syn2 + b * (T_STEPS * N1);
    float syn_nxt[7];
#pragma unroll
    for (int j = 0; j < 7; ++j) syn_nxt[j] = (j < NL2) ? syn2b[c + 32 * j] : 0.0f;

    __syncthreads();

    for (int t = 0; t < T_STEPS; ++t) {
        float syn_cur[7];
#pragma unroll
        for (int j = 0; j < 7; ++j) syn_cur[j] = syn_nxt[j];
        if (t + 1 < T_STEPS) {
#pragma unroll
            for (int j = 0; j < 7; ++j)
                if (j < NL2) syn_nxt[j] = syn2b[(t + 1) * N1 + c + 32 * j];
        }

        // ---- P1: layer 2 update, write s2 hi/lo to LDS ----
#pragma unroll
        for (int j = 0; j < 7; ++j) {
            if (j < NL2) {
                const int n = c + 32 * j;
                float mem2 = syn_cur[j];
#pragma unroll
                for (int k = 0; k < 9; ++k) mem2 = fmaf(-KS_TAIL[k], sl2h[k][j], mem2);
                const float s2  = sigm10(mem2 - 0.5f);
                const float sl2 = s2 * mem2;
#pragma unroll
                for (int k = 8; k > 0; --k) sl2h[k][j] = sl2h[k - 1][j];
                sl2h[0][j] = sl2;
                unsigned short hi, lo; split2(s2, hi, lo);
                const int off = g * 256 + (((n >> 3) ^ (g & 7)) * 8) + (n & 7);
                s2A[off]        = hi;
                s2A[4096 + off] = lo;
            }
        }
        __syncthreads();

        // ---- P2: MFMA GEMM2 (all 8 waves; wave = N-tile) ----
        {
            f32x4 a = (f32x4){0.f, 0.f, 0.f, 0.f};
            const int swz = m16 & 7;
#pragma unroll
            for (int ks = 0; ks < 7; ++ks) {
                const int gr = (4 * ks + j2) ^ swz;
                const bf16x8 ahv = *(const bf16x8*)&s2A[m16 * 256 + gr * 8];
                const bf16x8 alv = *(const bf16x8*)&s2A[4096 + m16 * 256 + gr * 8];
                a = __builtin_amdgcn_mfma_f32_16x16x32_bf16(ahv, bh[ks], a, 0, 0, 0);
                a = __builtin_amdgcn_mfma_f32_16x16x32_bf16(alv, bh[ks], a, 0, 0, 0);
                a = __builtin_amdgcn_mfma_f32_16x16x32_bf16(ahv, bl[ks], a, 0, 0, 0);
            }
#pragma unroll
            for (int q = 0; q < 4; ++q)
                h2buf[j2 * 4 + q][wv * 16 + m16] = swishf(a[q]);
        }
        __syncthreads();

        // ---- P3: layer 3 ----
#pragma unroll
        for (int j = 0; j < 4; ++j) {
            if (j < NL3) {
                const int m = c + 32 * j;
                const float hm = h2buf[g][m];
                float mem3 = KV[0] * hm;
#pragma unroll
                for (int k = 0; k < 9; ++k) mem3 = fmaf(KV[k + 1], h2h[k][j], mem3);
#pragma unroll
                for (int k = 0; k < 9; ++k) mem3 = fmaf(-KS_TAIL[k], sl3h[k][j], mem3);
                const float s3  = sigm10(mem3 - 0.5f);
                const float sl3 = s3 * mem3;
#pragma unroll
                for (int k = 8; k > 0; --k) { h2h[k][j] = h2h[k - 1][j]; sl3h[k][j] = sl3h[k - 1][j]; }
                h2h[0][j]  = hm;
                sl3h[0][j] = sl3;
                s3buf[g][m] = s3;
            }
        }
        __syncthreads();

        // ---- P4: GEMM3 (VALU, 176 threads) ----
        if (tid < 176) {
            const int e = tid / 11, o = tid - 11 * (tid / 11);
            float a = 0.0f;
#pragma unroll 5
            for (int m = 0; m < N2; m += 4) {
                const float4 sv = *(const float4*)&s3buf[e][m];
                const float4 wv4 = *(const float4*)&W3s[o * N2 + m];
                a = fmaf(sv.x, wv4.x, a);
                a = fmaf(sv.y, wv4.y, a);
                a = fmaf(sv.z, wv4.z, a);
                a = fmaf(sv.w, wv4.w, a);
            }
            h3buf[e * 12 + o] = swishf(a);
        }
        __syncthreads();

        // ---- P5: layer 4 (no trailing barrier needed) ----
        if (c < N3) {
            const float h3 = h3buf[g * 12 + c];
            float mem4 = KV[0] * h3;
#pragma unroll
            for (int k = 0; k < 9; ++k) mem4 = fmaf(KV[k + 1], h3h[k], mem4);
#pragma unroll
            for (int k = 0; k < 9; ++k) mem4 = fmaf(-KS_TAIL[k], sl4h[k], mem4);
            const float s4  = sigm10(mem4 - 0.5f);
            const float sl4 = s4 * mem4;
#pragma unroll
            for (int k = 8; k > 0; --k) { h3h[k] = h3h[k - 1]; sl4h[k] = sl4h[k - 1]; }
            h3h[0]  = h3;
            sl4h[0] = sl4;
            accum += s4;
        }
    }

    if (c < N3) out[b * N3 + c] = accum * 0.02f;
}

// ---------------------------------------------------------------------------
extern "C" void kernel_launch(void* const* d_in, const int* in_sizes, int n_in,
                              void* d_out, int out_size, void* d_ws, size_t ws_size,
                              hipStream_t stream) {
    const float* x  = (const float*)d_in[0];
    const float* W1 = (const float*)d_in[1];
    const float* W2 = (const float*)d_in[2];
    const float* W3 = (const float*)d_in[3];
    float* out = (float*)d_out;

    float* buf = (float*)d_ws;                                   // h1 -> syn2 in place
    unsigned short* W1pre  = (unsigned short*)(buf + (size_t)BATCH * T_STEPS * N1);
    unsigned short* W2pre2 = W1pre + 655360;                     // 57344 ushorts

    (void)hipFuncSetAttribute((const void*)gemm1_mfma,
                              hipFuncAttributeMaxDynamicSharedMemorySize, 131072);

    prep_w1<<<1280, 256, 0, stream>>>(W1, W1pre);
    prep_w2<<<224, 256, 0, stream>>>(W2, W2pre2);
    gemm1_mfma<<<(BATCH * T_STEPS) / 256, 512, 131072, stream>>>(x, W1pre, buf);
    conv_k<<<BATCH, 256, 0, stream>>>(buf);
    snn_scan2<<<BATCH / 16, 512, 0, stream>>>(buf, W2pre2, W3, out);
}